// Round 9
// baseline (2848.795 us; speedup 1.0000x reference)
//
#include <hip/hip_runtime.h>
#include <math.h>

// Problem constants (fixed by the harness).
#define BB 4096
#define TT 2048
#define LL 100

constexpr int NB = 16;       // batch items per block (= MFMA M)
constexpr int WG = 256;      // R9: 4 waves, 1 per SIMD; waves 0-2 own 2 tiles each
constexpr int KT = 7;        // K-tiles of 32 ext-slots (224 = 2*112)

#define L2E 1.44269504088896340736f

// R7 core: interleaved-K fused multiply. A_ext[2i]=bf16hi(h_i), A_ext[2i+1]=
// bf16lo(h_i); B_ext[2i]=bf16hi(w_i), B_ext[2i+1]=bf16mid(w_i). ONE pass of
// K_eff=224 computes (ahi+alo)·(bhi+bmid) = h·w + O(2^-18), 7 MFMA/gate.
// R9: wave-fusion. 4 waves (1/SIMD, waves_per_eu(1,1) -> 512-reg budget).
// Wave w<3 owns unit-tiles {w, w+3} (units 0..95, all valid); wave 3 owns
// pad tile 6 (units 96..99 + x-slot 100 + layer-2 carrier). Each wave: 7
// shared A-frag b128 reads, 28 MFMA for tile A, 28 for tile B, THEN
// update-A, update-B. update-A depends only on accA -> the compiler can
// issue its VALU under MFMA-B's pipe backpressure (separate pipes, m114):
// the [MFMA | trans] phases overlap WITHIN one in-order wave, which R8
// proved the inter-wave scheduler won't do on its own.
// LDS: single plane, granule (16B) = kt*64 + (row ^ (row>>3)); b128 reads
// conflict-free; h write-back: one ds_write_b32 per (tile,item) -- 2-way
// on writes (counted ~2.5e7 by PMC, free per m136 -- do not chase).
// SCHEDULE NOTE (R4 lesson): do NOT hand-interleave trans with the MFMAs
// that PRODUCE their inputs; independent blocks in program order only.
#define AG(kt, row) (((kt) * 64 + ((row) ^ ((row) >> 3))) * 4)

typedef short bf16x8 __attribute__((ext_vector_type(8)));
typedef float f32x4 __attribute__((ext_vector_type(4)));

union AF { int4 v; bf16x8 f; unsigned int w[4]; };

__device__ __forceinline__ float frcp(float x) { return __builtin_amdgcn_rcpf(x); }
__device__ __forceinline__ float fexp2(float x) {
#if __has_builtin(__builtin_amdgcn_exp2f)
    return __builtin_amdgcn_exp2f(x);
#else
    return exp2f(x);
#endif
}
// log2e pre-folded into weights/biases (v_exp_f32 IS 2^x).
__device__ __forceinline__ float sig2(float xp) { return frcp(1.0f + fexp2(-xp)); }
__device__ __forceinline__ float th2(float xpp) { return 1.0f - 2.0f * frcp(1.0f + fexp2(xpp)); }
__device__ __forceinline__ float ftanh_n(float x) { return th2(2.0f * L2E * x); }

__device__ __forceinline__ unsigned int cvt_pk_bf16(float lo, float hi) {
    unsigned int d;
    asm("v_cvt_pk_bf16_f32 %0, %1, %2" : "=v"(d) : "v"(lo), "v"(hi));
    return d;
}

// Frag layouts (HW-verified): A[m=lane&15][k=32kt+8quad+j];
// B[k][n=lane&15]; D col=lane&15, row=quad*4+reg.
// Unit u (= 16*tile + col16) maps to ext slots 2u,2u+1 = the two halfwords
// of dword (col16&3) in granule AG(tile, m + 16*(col16>>2)).
__global__ void __launch_bounds__(WG)
__attribute__((amdgpu_waves_per_eu(1, 1)))
lstm2_kernel(const float* __restrict__ input,   // [B,T]
             const float* __restrict__ W_ih1,   // [400,1]
             const float* __restrict__ W_hh1,   // [400,100]
             const float* __restrict__ b_ih1,   // [400]
             const float* __restrict__ b_hh1,   // [400]
             const float* __restrict__ W_ih2,   // [4,100]
             const float* __restrict__ W_hh2,   // [4,1]
             const float* __restrict__ b_ih2,   // [4]
             const float* __restrict__ b_hh2,   // [4]
             float* __restrict__ out)           // [B,T]
{
    __shared__ __align__(16) unsigned int afrag[2][KT * 256];   // 14 KB interleaved hi/lo

    const int tid = threadIdx.x;
    const int wave = tid >> 6;       // 0..3
    const int lane = tid & 63;
    const int col16 = lane & 15;
    const int quad = lane >> 4;
    const int bg0 = blockIdx.x * NB;

    // ---------------- init ----------------
    for (int i = tid; i < 2 * KT * 256; i += WG) (&afrag[0][0])[i] = 0u;

    // tile ownership: wave w<3 -> {w, w+3}; wave 3 -> {6}
    const int tA = (wave == 3) ? 6 : wave;
    const int tB = wave + 3;                 // valid only for wave<3
    const bool hasB = (wave < 3);
    const int uuA = 16 * tA + col16;
    const int uuB = 16 * tB + col16;         // <=95 when hasB
    const bool uvalidA = (uuA < LL);
    const bool l2lane = (wave == 3) && (col16 == 8);   // layer-2 carrier lanes
    const bool xlane = (wave == 3) && (col16 == 4);    // x-depositor (uuA==100)
    const bool wrA = (uuA <= 100);           // pads >100 never write

    // gate scales folding log2e (i,f,o: sigmoid; g: tanh needs 2x)
    const float gsc[4] = {L2E, L2E, 2.0f * L2E, L2E};

    // Persistent B-fragments, interleaved (hi,mid) along K; one set per tile.
    bf16x8 bbA[4][KT], bbB[4][KT];
#pragma unroll
    for (int g = 0; g < 4; ++g)
#pragma unroll
        for (int kt = 0; kt < KT; ++kt)
#pragma unroll
            for (int j = 0; j < 8; ++j) {
                const int k = 32 * kt + 8 * quad + j;   // ext slot
                const int i = k >> 1;                   // input unit
                // tile A weight
                float wA = 0.0f;
                if (i < LL) {
                    if (l2lane)        wA = W_ih2[g * LL + i] * gsc[g];
                    else if (uvalidA)  wA = W_hh1[(100 * g + uuA) * LL + i] * gsc[g];
                } else if (i == 100) {
                    if (!l2lane && uvalidA) wA = W_ih1[100 * g + uuA] * gsc[g];
                }
                // tile B weight (waves 0-2 only; all units valid)
                float wB = 0.0f;
                if (hasB) {
                    if (i < LL)        wB = W_hh1[(100 * g + uuB) * LL + i] * gsc[g];
                    else if (i == 100) wB = W_ih1[100 * g + uuB] * gsc[g];
                }
                const unsigned int hA = cvt_pk_bf16(wA, 0.0f) & 0xffffu;
                const unsigned int hB = cvt_pk_bf16(wB, 0.0f) & 0xffffu;
                if (!(k & 1)) {
                    bbA[g][kt][j] = (short)hA;
                    bbB[g][kt][j] = (short)hB;
                } else {
                    const float rA = wA - __uint_as_float(hA << 16);
                    const float rB = wB - __uint_as_float(hB << 16);
                    bbA[g][kt][j] = (short)(cvt_pk_bf16(rA, 0.0f) & 0xffffu);
                    bbB[g][kt][j] = (short)(cvt_pk_bf16(rB, 0.0f) & 0xffffu);
                }
            }

    // Exact fp32 biases as the MFMA C-input.
    f32x4 binitA[4], binitB[4];
#pragma unroll
    for (int g = 0; g < 4; ++g) {
        float bA = 0.0f, bB = 0.0f;
        if (l2lane)       bA = (b_ih2[g] + b_hh2[g]) * gsc[g];
        else if (uvalidA) bA = (b_ih1[100 * g + uuA] + b_hh1[100 * g + uuA]) * gsc[g];
        if (hasB)         bB = (b_ih1[100 * g + uuB] + b_hh1[100 * g + uuB]) * gsc[g];
        binitA[g] = (f32x4){bA, bA, bA, bA};
        binitB[g] = (f32x4){bB, bB, bB, bB};
    }

    float c1A[4] = {0.f, 0.f, 0.f, 0.f};
    float c1B[4] = {0.f, 0.f, 0.f, 0.f};

    // write offsets: one b32 per (tile, item r)
    int wofsA[4], wofsB[4];
#pragma unroll
    for (int r = 0; r < 4; ++r) {
        const int row = 4 * quad + r + 16 * (col16 >> 2);
        wofsA[r] = AG(tA, row) + (col16 & 3);
        wofsB[r] = AG(tB, row) + (col16 & 3);
    }

    // Layer-2 recurrent state (l2lane only; 4 items per lane, m = 4*quad+r)
    float wh2s[4], h2v[4] = {0.f, 0.f, 0.f, 0.f}, c2v[4] = {0.f, 0.f, 0.f, 0.f};
#pragma unroll
    for (int g = 0; g < 4; ++g)
        wh2s[g] = l2lane ? W_hh2[g] * gsc[g] : 0.0f;

    __syncthreads();

    // ---- prologue: deposit x_0 (hi|lo packed dword) into phase 0 ----
    if (xlane) {
#pragma unroll
        for (int r = 0; r < 4; ++r) {
            const int m = 4 * quad + r;
            const float x0 = input[(size_t)(bg0 + m) * TT];
            const unsigned int hh = cvt_pk_bf16(x0, x0);
            const float hf = __uint_as_float(hh << 16);
            afrag[0][wofsA[r]] = cvt_pk_bf16(x0, x0 - hf);
        }
    }
    __syncthreads();

    // ---------------- time loop (one barrier per step) ----------------
    for (int t = 0; t <= TT; ++t) {
        const int p = t & 1, pn = p ^ 1;

        // wave 3 also runs at t==TT to produce the final layer-2 output
        if (t < TT || wave == 3) {
            // x_{t+1} prefetch (4 lanes of wave 3; L2-resident lines).
            float xnext[4] = {0.f, 0.f, 0.f, 0.f};
            if (xlane && t + 1 < TT) {
#pragma unroll
                for (int r = 0; r < 4; ++r)
                    xnext[r] = input[(size_t)(bg0 + 4 * quad + r) * TT + (t + 1)];
            }

            // ---- A-frags (interleaved hi/lo of h1_{t-1}), shared by both tiles ----
            AF a[KT];
#pragma unroll
            for (int kt = 0; kt < KT; ++kt)
                a[kt].v = *(const int4*)&afrag[p][AG(kt, lane)];

            // ---- tile A MFMAs (28), bias preloaded via C ----
            f32x4 accA[4], accB[4];
#pragma unroll
            for (int g = 0; g < 4; ++g)
                accA[g] = __builtin_amdgcn_mfma_f32_16x16x32_bf16(a[0].f, bbA[g][0], binitA[g], 0, 0, 0);
#pragma unroll
            for (int kt = 1; kt < KT; ++kt)
#pragma unroll
                for (int g = 0; g < 4; ++g)
                    accA[g] = __builtin_amdgcn_mfma_f32_16x16x32_bf16(a[kt].f, bbA[g][kt], accA[g], 0, 0, 0);

            // ---- tile B MFMAs (28, waves 0-2) ----
            if (hasB) {
#pragma unroll
                for (int g = 0; g < 4; ++g)
                    accB[g] = __builtin_amdgcn_mfma_f32_16x16x32_bf16(a[0].f, bbB[g][0], binitB[g], 0, 0, 0);
#pragma unroll
                for (int kt = 1; kt < KT; ++kt)
#pragma unroll
                    for (int g = 0; g < 4; ++g)
                        accB[g] = __builtin_amdgcn_mfma_f32_16x16x32_bf16(a[kt].f, bbB[g][kt], accB[g], 0, 0, 0);
            }

            // ---- layer 2 (l2lane): accA[g][r] = b2 + dot(W_ih2[g], h1_{t-1}[4q+r]) ----
            if (l2lane && t >= 1) {
#pragma unroll
                for (int r = 0; r < 4; ++r) {
                    const float p0 = fmaf(wh2s[0], h2v[r], accA[0][r]);
                    const float p1 = fmaf(wh2s[1], h2v[r], accA[1][r]);
                    const float p2 = fmaf(wh2s[2], h2v[r], accA[2][r]);
                    const float p3 = fmaf(wh2s[3], h2v[r], accA[3][r]);
                    const float i2 = sig2(p0), f2 = sig2(p1), g2 = th2(p2), o2 = sig2(p3);
                    c2v[r] = f2 * c2v[r] + i2 * g2;
                    h2v[r] = o2 * ftanh_n(c2v[r]);
                    out[(size_t)(bg0 + 4 * quad + r) * TT + (t - 1)] = h2v[r];
                }
            }

            if (t < TT) {
                // ---- update tile A (independent of MFMA-B: overlaps it) ----
#pragma unroll
                for (int r = 0; r < 4; ++r) {
                    const float iv = sig2(accA[0][r]);
                    const float fv = sig2(accA[1][r]);
                    const float gv = th2(accA[2][r]);
                    const float ov = sig2(accA[3][r]);
                    const float c = fv * c1A[r] + iv * gv;
                    c1A[r] = c;
                    const float h = uvalidA ? (ov * ftanh_n(c)) : xnext[r];
                    if (wrA) {
                        const unsigned int hh = cvt_pk_bf16(h, h);   // low16 = bf16rn(h)
                        const float hf = __uint_as_float(hh << 16);
                        afrag[pn][wofsA[r]] = cvt_pk_bf16(h, h - hf); // hi | lo<<16
                    }
                }
                // ---- update tile B ----
                if (hasB) {
#pragma unroll
                    for (int r = 0; r < 4; ++r) {
                        const float iv = sig2(accB[0][r]);
                        const float fv = sig2(accB[1][r]);
                        const float gv = th2(accB[2][r]);
                        const float ov = sig2(accB[3][r]);
                        const float c = fv * c1B[r] + iv * gv;
                        c1B[r] = c;
                        const float h = ov * ftanh_n(c);             // all units valid
                        const unsigned int hh = cvt_pk_bf16(h, h);
                        const float hf = __uint_as_float(hh << 16);
                        afrag[pn][wofsB[r]] = cvt_pk_bf16(h, h - hf);
                    }
                }
            }
        }

        __syncthreads();   // h1_t (afrag[pn]) visible for step t+1
    }
}

extern "C" void kernel_launch(void* const* d_in, const int* in_sizes, int n_in,
                              void* d_out, int out_size, void* d_ws, size_t ws_size,
                              hipStream_t stream) {
    const float* input = (const float*)d_in[0];
    const float* W_ih1 = (const float*)d_in[1];
    const float* W_hh1 = (const float*)d_in[2];
    const float* b_ih1 = (const float*)d_in[3];
    const float* b_hh1 = (const float*)d_in[4];
    const float* W_ih2 = (const float*)d_in[5];
    const float* W_hh2 = (const float*)d_in[6];
    const float* b_ih2 = (const float*)d_in[7];
    const float* b_hh2 = (const float*)d_in[8];
    float* out = (float*)d_out;

    dim3 grid(BB / NB);   // 256 workgroups -> 1 per CU
    dim3 block(WG);       // 256 threads = 4 waves, 1 per SIMD
    lstm2_kernel<<<grid, block, 0, stream>>>(input, W_ih1, W_hh1, b_ih1, b_hh1,
                                             W_ih2, W_hh2, b_ih2, b_hh2, out);
}